// Round 1
// baseline (367.981 us; speedup 1.0000x reference)
//
#include <hip/hip_runtime.h>

#define NW 14
#define NL 3
#define DIM 16384            // 2^14
#define NPAIR (DIM / 2)
#define NGATES (NL * NW)     // 42 fused RY*RX gates
#define TPB 1024

struct Sched {
    unsigned short pm[NGATES];  // pair XOR mask per gate
    unsigned short vm[NGATES];  // value (parity) mask per gate: wire value = parity(i & vm)
    unsigned char  hh[NGATES];  // chosen pivot bit of pm (set bit, prefer >=6 for LDS banks)
    unsigned short zm[NW];      // final parity masks for <Z_w>
};

__global__ __launch_bounds__(TPB) void qsim_kernel(
    const float* __restrict__ state,
    const float* __restrict__ params,
    const float* __restrict__ head_w,
    const float* __restrict__ head_b,
    float* __restrict__ out,
    Sched sc)
{
    __shared__ float2 psi[DIM];          // 128 KB: full statevector
    __shared__ float4 umat[NGATES];      // fused gate matrices (a_re, a_im, b_re, b_im)
    __shared__ float  red[TPB / 64];

    const unsigned tid = threadIdx.x;

    // ---- Precompute fused U = RY(t2) * RX(t1); SU(2): [[a, b], [-conj(b), conj(a)]]
    // a = c1*c2 + i*s1*s2 ; b = -s2*c1 - i*c2*s1   (c=cos(t/2), s=sin(t/2))
    if (tid < NGATES) {
        float t1 = 0.5f * params[2 * tid + 0];
        float t2 = 0.5f * params[2 * tid + 1];
        float s1, c1, s2, c2;
        sincosf(t1, &s1, &c1);
        sincosf(t2, &s2, &c2);
        umat[tid] = make_float4(c1 * c2, s1 * s2, -s2 * c1, -c2 * s1);
    }

    // ---- Load state row -> LDS as complex (imag = 0)
    const float4* st4 = reinterpret_cast<const float4*>(state) + (size_t)blockIdx.x * (DIM / 4);
#pragma unroll
    for (int k = 0; k < DIM / 4 / TPB; ++k) {   // 4 iterations
        unsigned idx = tid + k * TPB;
        float4 v = st4[idx];
        unsigned base = idx * 4;
        psi[base + 0] = make_float2(v.x, 0.f);
        psi[base + 1] = make_float2(v.y, 0.f);
        psi[base + 2] = make_float2(v.z, 0.f);
        psi[base + 3] = make_float2(v.w, 0.f);
    }

    // ---- Apply 42 fused 1-qubit gates (CNOTs are deferred into the masks)
    for (int g = 0; g < NGATES; ++g) {
        __syncthreads();
        const float4  u   = umat[g];
        const unsigned m  = sc.pm[g];
        const unsigned vmk = sc.vm[g];
        const unsigned h  = sc.hh[g];
        const unsigned low = (1u << h) - 1u;
#pragma unroll
        for (int k = 0; k < NPAIR / TPB; ++k) {  // 8 iterations
            unsigned p  = tid + k * TPB;
            unsigned i0 = ((p & ~low) << 1) | (p & low);   // insert 0 at bit h
            unsigned i1 = i0 ^ m;                          // partner (bit h -> 1)
            // element with wire-value 0 plays the |0> role
            bool sw = (__popc(i0 & vmk) & 1);
            unsigned ia = sw ? i1 : i0;
            unsigned ib = sw ? i0 : i1;
            float2 x0 = psi[ia];
            float2 x1 = psi[ib];
            float2 y0, y1;
            y0.x =  u.x * x0.x - u.y * x0.y + u.z * x1.x - u.w * x1.y;
            y0.y =  u.x * x0.y + u.y * x0.x + u.z * x1.y + u.w * x1.x;
            y1.x = -u.z * x0.x - u.w * x0.y + u.x * x1.x + u.y * x1.y;
            y1.y = -u.z * x0.y + u.w * x0.x + u.x * x1.y - u.y * x1.x;
            psi[ia] = y0;
            psi[ib] = y1;
        }
    }

    __syncthreads();

    // ---- Measurement: out = sum_i |psi_i|^2 * coef(i) + head_b
    // coef(i) = sum_w head_w[w] * (1 - 2*parity(i & zm[w]))
    // i = k*1024 + tid  (tid = low 10 bits fixed per thread, k = high 4 bits)
    float    hws[NW];
    unsigned zhi[NW];
#pragma unroll
    for (int w = 0; w < NW; ++w) {
        unsigned zm = sc.zm[w];
        float    hw = head_w[w];
        hws[w] = (__popc(tid & zm & (TPB - 1)) & 1) ? -hw : hw;  // fold low-bit parity
        zhi[w] = zm >> 10;
    }
    float acc = 0.f;
#pragma unroll
    for (int k = 0; k < DIM / TPB; ++k) {       // 16 iterations
        float c = 0.f;
#pragma unroll
        for (int w = 0; w < NW; ++w)
            c += (__popc((unsigned)k & zhi[w]) & 1) ? -hws[w] : hws[w];
        float2 a = psi[k * TPB + tid];
        acc += (a.x * a.x + a.y * a.y) * c;
    }

    // ---- Block reduction
#pragma unroll
    for (int off = 32; off > 0; off >>= 1)
        acc += __shfl_down(acc, off, 64);
    const unsigned lane = tid & 63, wv = tid >> 6;
    if (lane == 0) red[wv] = acc;
    __syncthreads();
    if (tid == 0) {
        float tot = 0.f;
#pragma unroll
        for (int i = 0; i < TPB / 64; ++i) tot += red[i];
        out[blockIdx.x] = tot + head_b[0];
    }
}

// ---------------- host-side GF(2) schedule (circuit structure is fixed) ----------------
static void build_sched(Sched& sc) {
    unsigned A[NW];
    for (int w = 0; w < NW; ++w) A[w] = 1u << (NW - 1 - w);  // wire w <-> bit 13-w
    for (int l = 0; l < NL; ++l) {
        // invert M (rows = A[u]) over GF(2), augmented with identity in high bits
        unsigned rows[NW];
        for (int u = 0; u < NW; ++u) rows[u] = A[u] | (1u << (NW + u));
        for (int col = 0; col < NW; ++col) {
            int piv = col;
            while (piv < NW && !((rows[piv] >> col) & 1u)) ++piv;
            if (piv >= NW) continue;  // cannot happen: M stays invertible
            unsigned tmp = rows[col]; rows[col] = rows[piv]; rows[piv] = tmp;
            for (int r = 0; r < NW; ++r)
                if (r != col && ((rows[r] >> col) & 1u)) rows[r] ^= rows[col];
        }
        for (int w = 0; w < NW; ++w) {
            unsigned m = 0;
            for (int r = 0; r < NW; ++r) m |= ((rows[r] >> (NW + w)) & 1u) << r;  // col w of M^-1
            int g = l * NW + w;
            sc.pm[g] = (unsigned short)m;
            sc.vm[g] = (unsigned short)A[w];
            unsigned pick = (m & ~63u) ? (m & ~63u) : m;   // prefer pivot bit >= 6 (LDS banks)
            int h = 31 - __builtin_clz(pick);
            sc.hh[g] = (unsigned char)h;
        }
        // CNOT chain: (w -> w+1) sequentially, then (13 -> 0); target mask ^= control mask
        for (int w = 0; w < NW - 1; ++w) A[w + 1] ^= A[w];
        A[0] ^= A[NW - 1];
    }
    for (int w = 0; w < NW; ++w) sc.zm[w] = (unsigned short)A[w];
}

extern "C" void kernel_launch(void* const* d_in, const int* in_sizes, int n_in,
                              void* d_out, int out_size, void* d_ws, size_t ws_size,
                              hipStream_t stream) {
    const float* state  = (const float*)d_in[0];   // (1024, 16384) f32
    const float* params = (const float*)d_in[1];   // (3, 14, 2) f32
    const float* head_w = (const float*)d_in[2];   // (1, 14) f32
    const float* head_b = (const float*)d_in[3];   // (1,) f32
    float* out = (float*)d_out;                    // (1024,) f32

    Sched sc;
    build_sched(sc);

    qsim_kernel<<<out_size, TPB, 0, stream>>>(state, params, head_w, head_b, out, sc);
}

// Round 2
// 227.548 us; speedup vs baseline: 1.6172x; 1.6172x over previous
//
#include <hip/hip_runtime.h>
#include <cstring>

#define NW 14
#define NL 3
#define DIM 16384            // 2^14
#define NGATES (NL * NW)     // 42 fused RY*RX gates
#define TPB 1024
#define NPH 12               // phases: per layer 4+4+4+2 gates

typedef float v2f __attribute__((ext_vector_type(2)));

struct Phase {
    unsigned short sx[16];   // subset XORs of the phase's masks, indexed by 4-bit subset
    unsigned char  pos[12];  // non-pivot bit positions (ascending); 14-K used
    unsigned short vm[4];    // value-parity masks per gate
    unsigned char  cpar[4];  // per-gate: bit p = parity(sx[s0(p)] & vm)
    unsigned char  gbase;    // first gate id (into umat)
    unsigned char  _pad[3];
};

struct Sched {
    Phase ph[NPH];
    unsigned short zm[NW];   // final parity masks for <Z_w>
};

// Apply K gates (pair masks spanning a K-dim subspace) fully in registers.
// Each (tid, it) owns one 2^K-element coset; coset rep = idx bits spread over
// the non-pivot positions (pivot bits zero) -> valid transversal.
template<int K>
__device__ __forceinline__ void apply_phase(const Phase& ph, v2f* psi,
                                            const float4* umat, unsigned tid)
{
    constexpr int NLOC = 1 << K;
    constexpr int NIT  = DIM / (NLOC * TPB);
    __syncthreads();
#pragma unroll
    for (int it = 0; it < NIT; ++it) {
        const unsigned idx = tid + it * TPB;
        unsigned rep = 0;
#pragma unroll
        for (int b = 0; b < 14 - K; ++b)
            rep |= ((idx >> b) & 1u) << ph.pos[b];

        v2f x[NLOC];
#pragma unroll
        for (int s = 0; s < NLOC; ++s)
            x[s] = psi[rep ^ ph.sx[s]];

#pragma unroll
        for (int q = 0; q < K; ++q) {
            const float4  u  = umat[ph.gbase + q];   // (ax, ay, bx, by), uniform
            const unsigned vm = ph.vm[q];
            const unsigned cp = ph.cpar[q];
            const bool swt = __popc(rep & vm) & 1;
            const float aIs = swt ? -u.y : u.y;
            const float bRs = swt ? -u.z : u.z;
#pragma unroll
            for (int p = 0; p < NLOC / 2; ++p) {
                const int lowm = (1 << q) - 1;
                const int s0 = ((p & ~lowm) << 1) | (p & lowm);
                const int s1 = s0 | (1 << q);
                const bool  c0 = (cp >> p) & 1u;     // uniform
                const float aI = c0 ? -aIs : aIs;    // Im(a) with role sign
                const float bR = c0 ? -bRs : bRs;    // Re(b) with role sign
                const v2f x0 = x[s0], x1 = x[s1];
                const v2f x0s = (v2f){ -x0.y, x0.x };
                const v2f x1s = (v2f){ -x1.y, x1.x };
                // y0 = (ax,aI)*x0 + (bR,by)*x1 ; y1 = (-bR,by)*x0 + (ax,-aI)*x1
                x[s0] =  u.x * x0 + aI * x0s + bR  * x1 + u.w * x1s;
                x[s1] = (-bR) * x0 + u.w * x0s + u.x * x1 + (-aI) * x1s;
            }
        }
#pragma unroll
        for (int s = 0; s < NLOC; ++s)
            psi[rep ^ ph.sx[s]] = x[s];
    }
}

__global__ __launch_bounds__(TPB) void qsim_kernel(
    const float* __restrict__ state,
    const float* __restrict__ params,
    const float* __restrict__ head_w,
    const float* __restrict__ head_b,
    float* __restrict__ out,
    Sched sc)
{
    __shared__ v2f    psi[DIM];          // 128 KB
    __shared__ float4 umat[NGATES];
    __shared__ float  red[TPB / 64];

    const unsigned tid = threadIdx.x;

    // Fused U = RY(t2)*RX(t1) = [[a,b],[-conj(b),conj(a)]]
    // a = (c1c2, s1s2), b = (-s2c1, -c2s1)
    if (tid < NGATES) {
        float t1 = 0.5f * params[2 * tid + 0];
        float t2 = 0.5f * params[2 * tid + 1];
        float s1, c1, s2, c2;
        sincosf(t1, &s1, &c1);
        sincosf(t2, &s2, &c2);
        umat[tid] = make_float4(c1 * c2, s1 * s2, -s2 * c1, -c2 * s1);
    }

    // Stage state row -> LDS (imag = 0), coalesced float4
    const float4* st4 = reinterpret_cast<const float4*>(state) + (size_t)blockIdx.x * (DIM / 4);
#pragma unroll
    for (int k = 0; k < DIM / 4 / TPB; ++k) {
        unsigned idx = tid + k * TPB;
        float4 v = st4[idx];
        unsigned base = idx * 4;
        psi[base + 0] = (v2f){ v.x, 0.f };
        psi[base + 1] = (v2f){ v.y, 0.f };
        psi[base + 2] = (v2f){ v.z, 0.f };
        psi[base + 3] = (v2f){ v.w, 0.f };
    }

#pragma unroll
    for (int l = 0; l < NL; ++l) {
        apply_phase<4>(sc.ph[l * 4 + 0], psi, umat, tid);
        apply_phase<4>(sc.ph[l * 4 + 1], psi, umat, tid);
        apply_phase<4>(sc.ph[l * 4 + 2], psi, umat, tid);
        apply_phase<2>(sc.ph[l * 4 + 3], psi, umat, tid);
    }

    __syncthreads();

    // Measurement: out = sum_i |psi_i|^2 * coef(i) + head_b
    float    hws[NW];
    unsigned zhi[NW];
#pragma unroll
    for (int w = 0; w < NW; ++w) {
        unsigned zm = sc.zm[w];
        float    hw = head_w[w];
        hws[w] = (__popc(tid & zm & (TPB - 1)) & 1) ? -hw : hw;
        zhi[w] = zm >> 10;
    }
    float acc = 0.f;
#pragma unroll
    for (int k = 0; k < DIM / TPB; ++k) {
        float c = 0.f;
#pragma unroll
        for (int w = 0; w < NW; ++w)
            c += (__popc((unsigned)k & zhi[w]) & 1) ? -hws[w] : hws[w];
        v2f a = psi[k * TPB + tid];
        acc += (a.x * a.x + a.y * a.y) * c;
    }

#pragma unroll
    for (int off = 32; off > 0; off >>= 1)
        acc += __shfl_down(acc, off, 64);
    const unsigned lane = tid & 63, wv = tid >> 6;
    if (lane == 0) red[wv] = acc;
    __syncthreads();
    if (tid == 0) {
        float tot = 0.f;
#pragma unroll
        for (int i = 0; i < TPB / 64; ++i) tot += red[i];
        out[blockIdx.x] = tot + head_b[0];
    }
}

// ---------------- host-side GF(2) schedule ----------------
static void build_sched(Sched& sc) {
    unsigned A[NW];
    for (int w = 0; w < NW; ++w) A[w] = 1u << (NW - 1 - w);  // wire w <-> bit 13-w
    int pidx = 0;
    for (int l = 0; l < NL; ++l) {
        // invert M (rows = A[u]) over GF(2), augmented
        unsigned rows[NW];
        for (int u = 0; u < NW; ++u) rows[u] = A[u] | (1u << (NW + u));
        for (int col = 0; col < NW; ++col) {
            int piv = col;
            while (piv < NW && !((rows[piv] >> col) & 1u)) ++piv;
            if (piv >= NW) continue;
            unsigned tmp = rows[col]; rows[col] = rows[piv]; rows[piv] = tmp;
            for (int r = 0; r < NW; ++r)
                if (r != col && ((rows[r] >> col) & 1u)) rows[r] ^= rows[col];
        }
        unsigned m[NW];
        for (int w = 0; w < NW; ++w) {
            unsigned mk = 0;
            for (int r = 0; r < NW; ++r) mk |= ((rows[r] >> (NW + w)) & 1u) << r;
            m[w] = mk;   // pair mask of gate (l, w)
        }
        for (int g0 = 0; g0 < NW; g0 += 4) {
            int K = (NW - g0 >= 4) ? 4 : (NW - g0);
            Phase& P = sc.ph[pidx++];
            memset(&P, 0, sizeof(P));
            unsigned mm[4] = {0, 0, 0, 0};
            for (int q = 0; q < K; ++q) mm[q] = m[g0 + q];
            for (int s = 0; s < (1 << K); ++s) {
                unsigned v = 0;
                for (int q = 0; q < K; ++q) if ((s >> q) & 1) v ^= mm[q];
                P.sx[s] = (unsigned short)v;
            }
            // Gaussian elimination choosing HIGH pivot bits (keeps low index
            // bits thread-varying -> conflict-free LDS pattern)
            unsigned pivmask = 0, redv[4]; int pivpos[4];
            for (int q = 0; q < K; ++q) {
                unsigned r = mm[q];
                for (int j = 0; j < q; ++j)
                    if ((r >> pivpos[j]) & 1u) r ^= redv[j];
                int hb = 31 - __builtin_clz(r);
                pivpos[q] = hb; redv[q] = r; pivmask |= 1u << hb;
            }
            int n = 0;
            for (int b = 0; b < NW; ++b)
                if (!((pivmask >> b) & 1u)) P.pos[n++] = (unsigned char)b;
            for (int q = 0; q < K; ++q) {
                P.vm[q] = (unsigned short)A[g0 + q];
                unsigned lowm = (1u << q) - 1u, cp = 0;
                for (int p = 0; p < (1 << K) / 2; ++p) {
                    unsigned s0 = ((p & ~lowm) << 1) | (p & lowm);
                    if (__builtin_popcount(P.sx[s0] & A[g0 + q]) & 1) cp |= 1u << p;
                }
                P.cpar[q] = (unsigned char)cp;
            }
            P.gbase = (unsigned char)(l * NW + g0);
        }
        // CNOT chain (virtual): target parity mask ^= control mask
        for (int w = 0; w < NW - 1; ++w) A[w + 1] ^= A[w];
        A[0] ^= A[NW - 1];
    }
    for (int w = 0; w < NW; ++w) sc.zm[w] = (unsigned short)A[w];
}

extern "C" void kernel_launch(void* const* d_in, const int* in_sizes, int n_in,
                              void* d_out, int out_size, void* d_ws, size_t ws_size,
                              hipStream_t stream) {
    const float* state  = (const float*)d_in[0];   // (1024, 16384) f32
    const float* params = (const float*)d_in[1];   // (3, 14, 2) f32
    const float* head_w = (const float*)d_in[2];   // (1, 14) f32
    const float* head_b = (const float*)d_in[3];   // (1,) f32
    float* out = (float*)d_out;                    // (1024,) f32

    Sched sc;
    build_sched(sc);

    qsim_kernel<<<out_size, TPB, 0, stream>>>(state, params, head_w, head_b, out, sc);
}

// Round 4
// 139.279 us; speedup vs baseline: 2.6420x; 1.6338x over previous
//
#include <hip/hip_runtime.h>
#include <utility>

#define NW 14
#define NL 3
#define DIM 16384            // 2^14
#define NGATES (NL * NW)     // 42 fused RY*RX gates
#define TPB 1024
#define NPH (NL * 4)         // phases: per layer 4+4+4+2 gates

typedef float v2f __attribute__((ext_vector_type(2)));

struct Phase {
    unsigned short sx[16]  = {};  // subset XORs of the phase's masks
    unsigned char  pos[12] = {};  // non-pivot bit positions (ascending)
    unsigned short vm[4]   = {};  // value-parity masks per gate
    unsigned char  cpar[4] = {};  // per-gate per-pair compile-time role bits
    unsigned char  gbase   = 0;   // first gate id
    unsigned char  K       = 0;   // gates in this phase
};
struct Sched {
    Phase          ph[NPH] = {};
    unsigned short zm[NW]  = {};  // final parity masks for <Z_w>
};

// ---- LDS swizzle sigma(i) = i ^ f(i), f linear over GF(2) from index bits 4..9
// into bank bits 0..3: g(4)=3 g(5)=2 g(6)=5 g(7)=10 g(8)=1 g(9)=2.
// Verified by hand against all 12 phases' pivot sets + staging + measurement:
// every 16-lane quarter-wave hits all 16 bank-pairs (rank-4 lane->bank map).
__host__ __device__ constexpr unsigned foldf(unsigned i) {
    unsigned u = i >> 4;   // u0=i4 u1=i5 u2=i6 u3=i7 u4=i8 u5=i9
    return ((u ^ (u >> 2) ^ (u >> 4)) & 1u)                     // bit0 = i4^i6^i8
         | (((u ^ (u >> 1) ^ (u >> 3) ^ (u >> 5)) & 1u) << 1)   // bit1 = i4^i5^i7^i9
         | (u & 12u);                                           // bit2 = i6, bit3 = i7
}
__host__ __device__ constexpr unsigned sigma(unsigned i) { return i ^ foldf(i); }

// ---------------- compile-time GF(2) schedule ----------------
constexpr Sched build_sched() {
    Sched sc{};
    unsigned A[NW] = {};
    for (int w = 0; w < NW; ++w) A[w] = 1u << (NW - 1 - w);  // wire w <-> bit 13-w
    int pidx = 0;
    for (int l = 0; l < NL; ++l) {
        unsigned rows[NW] = {};
        for (int u = 0; u < NW; ++u) rows[u] = A[u] | (1u << (NW + u));
        for (int col = 0; col < NW; ++col) {
            int piv = col;
            while (piv < NW && !((rows[piv] >> col) & 1u)) ++piv;
            if (piv >= NW) continue;
            unsigned tmp = rows[col]; rows[col] = rows[piv]; rows[piv] = tmp;
            for (int r = 0; r < NW; ++r)
                if (r != col && ((rows[r] >> col) & 1u)) rows[r] ^= rows[col];
        }
        unsigned m[NW] = {};
        for (int w = 0; w < NW; ++w) {
            unsigned mk = 0;
            for (int r = 0; r < NW; ++r) mk |= ((rows[r] >> (NW + w)) & 1u) << r;
            m[w] = mk;  // pair mask of gate (l, w)
        }
        for (int g0 = 0; g0 < NW; g0 += 4) {
            int K = (NW - g0 >= 4) ? 4 : (NW - g0);
            Phase& P = sc.ph[pidx++];
            unsigned mm[4] = { 0, 0, 0, 0 };
            for (int q = 0; q < K; ++q) mm[q] = m[g0 + q];
            for (int s = 0; s < (1 << K); ++s) {
                unsigned v = 0;
                for (int q = 0; q < K; ++q) if ((s >> q) & 1) v ^= mm[q];
                P.sx[s] = (unsigned short)v;
            }
            // Gaussian elimination preferring HIGH pivot bits
            unsigned pivmask = 0, redv[4] = {}; int pivpos[4] = {};
            for (int q = 0; q < K; ++q) {
                unsigned r = mm[q];
                for (int j = 0; j < q; ++j)
                    if ((r >> pivpos[j]) & 1u) r ^= redv[j];
                int hb = 31 - __builtin_clz(r);
                pivpos[q] = hb; redv[q] = r; pivmask |= 1u << hb;
            }
            int n = 0;
            for (int b = 0; b < NW; ++b)
                if (!((pivmask >> b) & 1u)) P.pos[n++] = (unsigned char)b;
            for (int q = 0; q < K; ++q) {
                P.vm[q] = (unsigned short)A[g0 + q];
                unsigned lowm = (1u << q) - 1u, cp = 0;
                for (int p = 0; p < (1 << K) / 2; ++p) {
                    unsigned s0 = ((p & ~lowm) << 1) | (p & lowm);
                    if (__builtin_popcount(P.sx[s0] & A[g0 + q]) & 1) cp |= 1u << p;
                }
                P.cpar[q] = (unsigned char)cp;
            }
            P.gbase = (unsigned char)(l * NW + g0);
            P.K = (unsigned char)K;
        }
        for (int w = 0; w < NW - 1; ++w) A[w + 1] ^= A[w];  // virtual CNOT chain
        A[0] ^= A[NW - 1];
    }
    for (int w = 0; w < NW; ++w) sc.zm[w] = (unsigned short)A[w];
    return sc;
}
constexpr Sched SC = build_sched();

// ---------------- static_for ----------------
template<class F, unsigned... I>
__device__ __forceinline__ void static_for_impl(F&& f, std::integer_sequence<unsigned, I...>) {
    (f(std::integral_constant<unsigned, I>{}), ...);
}
template<unsigned N, class F>
__device__ __forceinline__ void static_for(F&& f) {
    static_for_impl(static_cast<F&&>(f), std::make_integer_sequence<unsigned, N>{});
}

// ---------------- packed complex mul/mac ----------------
// cmul: y = k' * x  (complex), k' = (s0*k.lo, s1*k.hi), s=+1/-1 per NEGLO/NEGHI.
// inst1 (mul, init): y.lo = (±k.lo)*x.lo ; y.hi = (±k.lo)*x.hi
// inst2 (fma)      : y.lo += (±k.hi)*(-x.hi) ; y.hi += (±k.hi)*x.lo
template<int NEGLO, int NEGHI>
__device__ __forceinline__ v2f cmul(v2f k, v2f x) {
    v2f y;
    if constexpr (!NEGLO)
        asm("v_pk_mul_f32 %0, %1, %2 op_sel:[0,0] op_sel_hi:[0,1]"
            : "=&v"(y) : "v"(k), "v"(x));
    else
        asm("v_pk_mul_f32 %0, %1, %2 op_sel:[0,0] op_sel_hi:[0,1] neg_lo:[1,0] neg_hi:[1,0]"
            : "=&v"(y) : "v"(k), "v"(x));
    if constexpr (!NEGHI)
        asm("v_pk_fma_f32 %0, %1, %2, %0 op_sel:[1,1,0] op_sel_hi:[1,0,1] neg_lo:[0,1,0]"
            : "+v"(y) : "v"(k), "v"(x));
    else
        asm("v_pk_fma_f32 %0, %1, %2, %0 op_sel:[1,1,0] op_sel_hi:[1,0,1] neg_lo:[1,1,0] neg_hi:[1,0,0]"
            : "+v"(y) : "v"(k), "v"(x));
    return y;
}
// cmac: y += k' * x  (same sign conventions)
template<int NEGLO, int NEGHI>
__device__ __forceinline__ void cmac(v2f& y, v2f k, v2f x) {
    if constexpr (!NEGLO)
        asm("v_pk_fma_f32 %0, %1, %2, %0 op_sel:[0,0,0] op_sel_hi:[0,1,1]"
            : "+v"(y) : "v"(k), "v"(x));
    else
        asm("v_pk_fma_f32 %0, %1, %2, %0 op_sel:[0,0,0] op_sel_hi:[0,1,1] neg_lo:[1,0,0] neg_hi:[1,0,0]"
            : "+v"(y) : "v"(k), "v"(x));
    if constexpr (!NEGHI)
        asm("v_pk_fma_f32 %0, %1, %2, %0 op_sel:[1,1,0] op_sel_hi:[1,0,1] neg_lo:[0,1,0]"
            : "+v"(y) : "v"(k), "v"(x));
    else
        asm("v_pk_fma_f32 %0, %1, %2, %0 op_sel:[1,1,0] op_sel_hi:[1,0,1] neg_lo:[1,1,0] neg_hi:[1,0,0]"
            : "+v"(y) : "v"(k), "v"(x));
}

// ---------------- one phase: K gates fully in registers ----------------
template<int PIDX>
__device__ __forceinline__ void apply_phase(char* psiB, const float4* __restrict__ umat,
                                            unsigned tid)
{
    constexpr int K    = SC.ph[PIDX].K;
    constexpr int NLOC = 1 << K;
    constexpr int NIT  = DIM / (NLOC * TPB);
    __syncthreads();
#pragma unroll
    for (int it = 0; it < NIT; ++it) {
        const unsigned idx = tid + it * TPB;
        unsigned rep = 0;
#pragma unroll
        for (int b = 0; b < 14 - K; ++b)
            rep |= ((idx >> b) & 1u) << SC.ph[PIDX].pos[b];
        const unsigned srep8 = (rep ^ foldf(rep)) << 3;

        v2f x[NLOC];
        static_for<NLOC>([&](auto S) {
            constexpr unsigned s   = decltype(S)::value;
            constexpr unsigned off = sigma(SC.ph[PIDX].sx[s]) << 3;
            x[s] = *(const v2f*)(psiB + (srep8 ^ off));
        });

        static_for<K>([&](auto Qc) {
            constexpr unsigned q  = decltype(Qc)::value;
            constexpr unsigned vm = SC.ph[PIDX].vm[q];
            constexpr unsigned cp = SC.ph[PIDX].cpar[q];
            const float4 u = umat[SC.ph[PIDX].gbase + q];
            const unsigned sm = ((unsigned)__popc(rep & vm)) << 31;  // coset parity sign
            v2f A, B;  // A = (ar, ai^s), B = (br^s, bi)
            A.x = u.x; A.y = __uint_as_float(__float_as_uint(u.y) ^ sm);
            B.x = __uint_as_float(__float_as_uint(u.z) ^ sm); B.y = u.w;
            static_for<NLOC / 2>([&](auto Pc) {
                constexpr unsigned p    = decltype(Pc)::value;
                constexpr unsigned lowm = (1u << q) - 1u;
                constexpr unsigned s0   = ((p & ~lowm) << 1) | (p & lowm);
                constexpr unsigned s1   = s0 | (1u << q);
                constexpr bool     c    = (cp >> p) & 1u;
                const v2f x0 = x[s0], x1 = x[s1];
                if constexpr (!c) {
                    // y0 = ( ax, A.y)x0 + ( B.x, by)x1 ; y1 = (-B.x, by)x0 + (ax, -A.y)x1
                    v2f y0 = cmul<0, 0>(A, x0); cmac<0, 0>(y0, B, x1);
                    v2f y1 = cmul<1, 0>(B, x0); cmac<0, 1>(y1, A, x1);
                    x[s0] = y0; x[s1] = y1;
                } else {
                    // roles swapped: y0 = (ax, -A.y)x0 + (-B.x, by)x1 ; y1 = (B.x, by)x0 + (ax, A.y)x1
                    v2f y0 = cmul<0, 1>(A, x0); cmac<1, 0>(y0, B, x1);
                    v2f y1 = cmul<0, 0>(B, x0); cmac<0, 0>(y1, A, x1);
                    x[s0] = y0; x[s1] = y1;
                }
            });
        });

        static_for<NLOC>([&](auto S) {
            constexpr unsigned s   = decltype(S)::value;
            constexpr unsigned off = sigma(SC.ph[PIDX].sx[s]) << 3;
            *(v2f*)(psiB + (srep8 ^ off)) = x[s];
        });
    }
}

__global__ __launch_bounds__(TPB) void qsim_kernel(
    const float* __restrict__ state,
    const float* __restrict__ params,
    const float* __restrict__ head_w,
    const float* __restrict__ head_b,
    float* __restrict__ out)
{
    __shared__ v2f    psi[DIM];          // 128 KB
    __shared__ float4 umat[NGATES];
    __shared__ float  red[TPB / 64];
    char* psiB = (char*)psi;

    const unsigned tid = threadIdx.x;

    // Fused U = RY(t2)*RX(t1) = [[a,b],[-conj(b),conj(a)]]; a=(c1c2,s1s2), b=(-s2c1,-c2s1)
    if (tid < NGATES) {
        float t1 = 0.5f * params[2 * tid + 0];
        float t2 = 0.5f * params[2 * tid + 1];
        float s1, c1, s2, c2;
        sincosf(t1, &s1, &c1);
        sincosf(t2, &s2, &c2);
        umat[tid] = make_float4(c1 * c2, s1 * s2, -s2 * c1, -c2 * s1);
    }

    // Stage state row -> LDS at swizzled indices (imag = 0)
    const float4* st4 = reinterpret_cast<const float4*>(state) + (size_t)blockIdx.x * (DIM / 4);
#pragma unroll
    for (int k = 0; k < DIM / 4 / TPB; ++k) {
        unsigned idx = tid + k * TPB;
        float4 v = st4[idx];
        unsigned a = idx * 4;
        unsigned b = (a ^ foldf(a)) << 3;   // foldf depends on bits 4..9 only (t-invariant)
        *(v2f*)(psiB + (b ^ 0))  = (v2f){ v.x, 0.f };
        *(v2f*)(psiB + (b ^ 8))  = (v2f){ v.y, 0.f };
        *(v2f*)(psiB + (b ^ 16)) = (v2f){ v.z, 0.f };
        *(v2f*)(psiB + (b ^ 24)) = (v2f){ v.w, 0.f };
    }

    static_for<NPH>([&](auto Pi) {
        apply_phase<(int)decltype(Pi)::value>(psiB, umat, tid);
    });

    __syncthreads();

    // Measurement: out = sum_i |psi_i|^2 * coef(i) + head_b
    const unsigned baseB = (tid ^ foldf(tid)) << 3;
    float hws[NW];
#pragma unroll
    for (int w = 0; w < NW; ++w) {
        float hw = head_w[w];
        hws[w] = (__popc(tid & (SC.zm[w] & (TPB - 1))) & 1) ? -hw : hw;
    }
    float acc = 0.f;
#pragma unroll
    for (int k = 0; k < DIM / TPB; ++k) {
        float c = 0.f;
#pragma unroll
        for (int w = 0; w < NW; ++w)
            c += (__popc((unsigned)k & (SC.zm[w] >> 10)) & 1) ? -hws[w] : hws[w];
        v2f a = *(const v2f*)(psiB + baseB + k * (TPB * 8));
        acc += (a.x * a.x + a.y * a.y) * c;
    }

#pragma unroll
    for (int off = 32; off > 0; off >>= 1)
        acc += __shfl_down(acc, off, 64);
    const unsigned lane = tid & 63, wv = tid >> 6;
    if (lane == 0) red[wv] = acc;
    __syncthreads();
    if (tid == 0) {
        float tot = 0.f;
#pragma unroll
        for (int i = 0; i < TPB / 64; ++i) tot += red[i];
        out[blockIdx.x] = tot + head_b[0];
    }
}

extern "C" void kernel_launch(void* const* d_in, const int* in_sizes, int n_in,
                              void* d_out, int out_size, void* d_ws, size_t ws_size,
                              hipStream_t stream) {
    const float* state  = (const float*)d_in[0];   // (1024, 16384) f32
    const float* params = (const float*)d_in[1];   // (3, 14, 2) f32
    const float* head_w = (const float*)d_in[2];   // (1, 14) f32
    const float* head_b = (const float*)d_in[3];   // (1,) f32
    float* out = (float*)d_out;                    // (1024,) f32

    qsim_kernel<<<out_size, TPB, 0, stream>>>(state, params, head_w, head_b, out);
}